// Round 1
// 389.285 us; speedup vs baseline: 1.1413x; 1.1413x over previous
//
#include <hip/hip_runtime.h>
#include <hip/hip_fp16.h>
#include <math.h>

#define THREADS 256
#define RPB 32
#define NBLK (65536 / RPB)   // 2048 blocks

// ---- workspace layout (float offsets) ----
// W1 images: 16 chunks, each [jj=0..31][c=0..67] padded to 3072 floats (12288 B)
//   ws1[it*3072 + jj*68 + c] = W1[c*513 + it*32 + jj]   (c<64; pad cols garbage, never read)
// W2 images: 4 chunks, each 8192 floats, pre-XOR-swizzled LDS image
// W1 last column (epsilon weights): 64 floats
#define WS_W1    0
#define WS_W1_CH 3072
#define WS_W2    (16 * WS_W1_CH)          // 49152
#define WS_W2_CH 8192
#define WS_W1L   (WS_W2 + 4 * WS_W2_CH)   // 81920
// total 81984 floats = 327936 bytes of d_ws

// ---- LDS layout (bytes) ----
// s_t (33 KB fp16 tanh buffer) eliminated: tanh lives in 32 half2 VGPRs per
// thread and the epilogue is fused into the GEMM2 thread mapping.
#define OFF_W    0
#define SZ_W     32768                    // union: W1 dbuf 2x12288 | W2 chunk 32768
#define W1BUF_B  12288
#define OFF_H1   (OFF_W + SZ_W)           // 32768
#define SZ_H1    (RPB * 68 * 4)           // 8704
#define OFF_CI   (OFF_H1 + SZ_H1)         // 41472
#define SZ_CI    2048
#define OFF_EPS  (OFF_CI + SZ_CI)         // 43520
#define OFF_EPSC (OFF_EPS + 128)          // 43648
#define SMEM_BYTES (OFF_EPSC + 128)       // 43776 B -> 3 blocks/CU (160 KiB LDS)

__device__ __forceinline__ float fast_tanh(float z) {
    // tanh(z) = 1 - 2/(e^{2z}+1); saturates correctly for |z| large (inf/0 paths)
    float e = __expf(2.0f * z);
    return fmaf(-2.0f, __builtin_amdgcn_rcpf(e + 1.0f), 1.0f);
}

// ---------------- prep: materialize LDS images of weights in ws ----------------
__global__ __launch_bounds__(256) void prep_kernel(
    const float* __restrict__ W1, const float* __restrict__ W2,
    float* __restrict__ ws)
{
    int tid = blockIdx.x * 256 + threadIdx.x;   // 0..32767, grid = 128 blocks
    // W1 chunk images
    {
        int it = tid >> 11;           // /2048 -> 0..15
        int rem = tid & 2047;
        int jj = rem >> 6, c = rem & 63;
        ws[WS_W1 + it * WS_W1_CH + jj * 68 + c] = W1[c * 513 + it * 32 + jj];
    }
    // W2 swizzled chunk images (linear read, swizzled write)
    {
        int j = tid & 3, kf4 = (tid >> 2) & 15, n = (tid >> 6) & 127, ch = tid >> 13;
        int swz = kf4 ^ ((9 * (n >> 2) + (n & 3)) & 15);
        ws[WS_W2 + ch * WS_W2_CH + n * 64 + swz * 4 + j] = W2[tid];
    }
    if (tid < 64) ws[WS_W1L + tid] = W1[tid * 513 + 512];
}

// ---------------- main fused kernel ----------------
__global__ __launch_bounds__(THREADS, 3) void fused_rgu(
    const float* __restrict__ x, const float* __restrict__ xcons,
    const float* __restrict__ cap, const float* __restrict__ b1,
    const float* __restrict__ b2, const float* __restrict__ ws,
    float* __restrict__ out)
{
    extern __shared__ __align__(16) char smem[];
    float*          s_w    = (float*)(smem + OFF_W);
    float*          s_h1   = (float*)(smem + OFF_H1);
    float*          s_ci   = (float*)(smem + OFF_CI);
    float*          s_eps  = (float*)(smem + OFF_EPS);
    float*          s_epsC = (float*)(smem + OFF_EPSC);

    const int t    = threadIdx.x;
    const int lane = t & 63;
    const int wv   = t >> 6;
    const long r0  = (long)blockIdx.x * RPB;

    // stage W1 chunk 0 into buffer 0 early (overlaps the eps phase's global loads)
    {
        const float4* src = (const float4*)(ws + WS_W1);
        float4* dst = (float4*)(smem + OFF_W);
        dst[t] = src[t]; dst[t + 256] = src[t + 256]; dst[t + 512] = src[t + 512];
    }

    // ---- P0: cap regs, capinv, capSum ----
    float4 capA = *(const float4*)(cap + 4 * lane);
    float4 capB = *(const float4*)(cap + 256 + 4 * lane);
    {
        float c0 = cap[t], c1 = cap[t + 256];
        s_ci[t] = 1.0f / c0; s_ci[t + 256] = 1.0f / c1;
    }
    float capSum;
    {
        float p = capA.x + capA.y + capA.z + capA.w
                + capB.x + capB.y + capB.z + capB.w;
        #pragma unroll
        for (int m = 1; m < 64; m <<= 1) p += __shfl_xor(p, m, 64);
        capSum = p;
    }
    const float invCapSum = 1.0f / capSum;

    // ---- P1: epsilon per row (wave wv -> rows wv*8..+7) ----
    #pragma unroll
    for (int rr = 0; rr < 8; ++rr) {
        int r = wv * 8 + rr;
        const float* xr = x + (r0 + r) * 512;
        float4 xA = *(const float4*)(xr + 4 * lane);
        float4 xB = *(const float4*)(xr + 256 + 4 * lane);
        float d = fmaf(xA.x, capA.x, fmaf(xA.y, capA.y,
                  fmaf(xA.z, capA.z, fmaf(xA.w, capA.w,
                  fmaf(xB.x, capB.x, fmaf(xB.y, capB.y,
                  fmaf(xB.z, capB.z, xB.w * capB.w)))))));
        #pragma unroll
        for (int m = 1; m < 64; m <<= 1) d += __shfl_xor(d, m, 64);
        if (lane == 0) {
            float epsC = fmaf(xcons[r0 + r], capSum, -d);   // eps * capSum
            s_epsC[r] = epsC;
            s_eps[r]  = epsC * invCapSum;
        }
    }
    __syncthreads();   // eps visible + W1 chunk 0 staged

    // ---- GEMM1: h1[32][64] = relu(x[32][512] @ W1T + eps*w1last + b1) ----
    // t = rg*16 + cg : rows 2rg..2rg+1, cols 4cg..4cg+3. acc[2][4], no k-split.
    const int rg = t >> 4;
    const int cg = t & 15;
    float acc0[4] = {0.f, 0.f, 0.f, 0.f};
    float acc1[4] = {0.f, 0.f, 0.f, 0.f};
    {
        const float* xg0 = x + (r0 + 2 * rg) * 512;
        const float* xg1 = xg0 + 512;
        for (int it = 0; it < 16; ++it) {
            const int b = it & 1;
            if (it < 15) {   // prefetch next chunk into other buffer (no extra barrier)
                const float4* src = (const float4*)(ws + WS_W1 + (it + 1) * WS_W1_CH);
                float4* dst = (float4*)(smem + OFF_W + (b ^ 1) * W1BUF_B);
                dst[t] = src[t]; dst[t + 256] = src[t + 256]; dst[t + 512] = src[t + 512];
            }
            const float* w = (const float*)(smem + OFF_W + b * W1BUF_B);
            const int k0 = it * 32;
            #pragma unroll
            for (int j4 = 0; j4 < 8; ++j4) {
                float4 xv0 = *(const float4*)(xg0 + k0 + j4 * 4);
                float4 xv1 = *(const float4*)(xg1 + k0 + j4 * 4);
                const float* wb = &w[(j4 * 4) * 68 + 4 * cg];
                float wr[4][4];
                #pragma unroll
                for (int dj = 0; dj < 4; ++dj) {
                    float4 w4 = *(const float4*)(wb + dj * 68);
                    wr[dj][0] = w4.x; wr[dj][1] = w4.y; wr[dj][2] = w4.z; wr[dj][3] = w4.w;
                }
                #pragma unroll
                for (int m = 0; m < 4; ++m) {
                    acc0[m] = fmaf(xv0.x, wr[0][m], fmaf(xv0.y, wr[1][m],
                              fmaf(xv0.z, wr[2][m], fmaf(xv0.w, wr[3][m], acc0[m]))));
                    acc1[m] = fmaf(xv1.x, wr[0][m], fmaf(xv1.y, wr[1][m],
                              fmaf(xv1.z, wr[2][m], fmaf(xv1.w, wr[3][m], acc1[m]))));
                }
            }
            __syncthreads();
        }
        // bias + eps-column + relu in registers, single b128 store per row
        float4 b1v = *(const float4*)(b1 + 4 * cg);
        float4 wl  = *(const float4*)(ws + WS_W1L + 4 * cg);
        #pragma unroll
        for (int i = 0; i < 2; ++i) {
            float e = s_eps[2 * rg + i];
            const float* a = i ? acc1 : acc0;
            float4 h;
            h.x = fmaxf(a[0] + fmaf(e, wl.x, b1v.x), 0.f);
            h.y = fmaxf(a[1] + fmaf(e, wl.y, b1v.y), 0.f);
            h.z = fmaxf(a[2] + fmaf(e, wl.z, b1v.z), 0.f);
            h.w = fmaxf(a[3] + fmaf(e, wl.w, b1v.w), 0.f);
            *(float4*)&s_h1[(2 * rg + i) * 68 + 4 * cg] = h;
        }
    }

    // ---- GEMM2 + tanh + rowsum: z[32][512] = h1 @ W2T + b2 ----
    // t = rg2*32 + ng : rows rg2*4..+3, cols 4ng..4ng+3 per 128-col chunk.
    // tanh values stay in registers: tp[ch][i][0..1] = half2-packed (t0,t1),(t2,t3).
    const int ng  = t & 31;
    const int rg2 = t >> 5;
    float rsum[4] = {0.f, 0.f, 0.f, 0.f};
    unsigned tp[4][4][2];   // 32 VGPRs; ALL indexing static via full unroll
    #pragma unroll
    for (int ch = 0; ch < 4; ++ch) {
        __syncthreads();   // prior users of s_w done (covers h1 stores for ch=0 too)
        {
            const float4* src = (const float4*)(ws + WS_W2 + ch * WS_W2_CH);
            float4* dst = (float4*)(smem + OFF_W);
            #pragma unroll
            for (int e8 = 0; e8 < 8; ++e8) dst[e8 * 256 + t] = src[e8 * 256 + t];
        }
        __syncthreads();
        const int n0 = ch * 128;
        float4 b2v = *(const float4*)(b2 + n0 + 4 * ng);
        float za[4][4];
        #pragma unroll
        for (int i = 0; i < 4; ++i) {
            za[i][0] = b2v.x; za[i][1] = b2v.y; za[i][2] = b2v.z; za[i][3] = b2v.w;
        }
        #pragma unroll
        for (int kf4 = 0; kf4 < 16; ++kf4) {
            float hr[4][4];
            #pragma unroll
            for (int i = 0; i < 4; ++i) {
                float4 h = *(const float4*)&s_h1[(rg2 * 4 + i) * 68 + kf4 * 4];
                hr[i][0] = h.x; hr[i][1] = h.y; hr[i][2] = h.z; hr[i][3] = h.w;
            }
            float wr2[4][4];
            #pragma unroll
            for (int m = 0; m < 4; ++m) {
                int nl = 4 * ng + m;
                int swz = kf4 ^ ((9 * ng + m) & 15);
                float4 w = *(const float4*)&s_w[nl * 64 + swz * 4];
                wr2[m][0] = w.x; wr2[m][1] = w.y; wr2[m][2] = w.z; wr2[m][3] = w.w;
            }
            #pragma unroll
            for (int i = 0; i < 4; ++i)
                #pragma unroll
                for (int m = 0; m < 4; ++m)
                    za[i][m] = fmaf(hr[i][0], wr2[m][0], fmaf(hr[i][1], wr2[m][1],
                               fmaf(hr[i][2], wr2[m][2], fmaf(hr[i][3], wr2[m][3], za[i][m]))));
        }
        #pragma unroll
        for (int i = 0; i < 4; ++i) {
            float t0 = fast_tanh(za[i][0]);
            float t1 = fast_tanh(za[i][1]);
            float t2 = fast_tanh(za[i][2]);
            float t3 = fast_tanh(za[i][3]);
            rsum[i] += (t0 + t1) + (t2 + t3);
            __half2 h01 = __floats2half2_rn(t0, t1);
            __half2 h23 = __floats2half2_rn(t2, t3);
            tp[ch][i][0] = *(unsigned*)&h01;
            tp[ch][i][1] = *(unsigned*)&h23;
        }
    }

    // reduce rowsums across the 32 ng lanes (within wave halves); every lane
    // ends up holding S for its rows -> rs in-register, no LDS, no barrier.
    float rs[4];
    #pragma unroll
    for (int i = 0; i < 4; ++i) {
        float s = rsum[i];
        #pragma unroll
        for (int msk = 1; msk < 32; msk <<= 1) s += __shfl_xor(s, msk, 64);
        rs[i] = s_epsC[rg2 * 4 + i] / s;   // eps*capSum / S
    }

    // ---- epilogue (fused, per-thread): out = x + t * (epsC/S) * capinv ----
    // For fixed (ch,i) a wave writes 2 rows x 512B contiguous -> fully coalesced.
    #pragma unroll
    for (int ch = 0; ch < 4; ++ch) {
        const int c = ch * 128 + 4 * ng;
        float4 ci = *(const float4*)&s_ci[c];
        #pragma unroll
        for (int i = 0; i < 4; ++i) {
            const int r = rg2 * 4 + i;
            float4 xv = *(const float4*)(x + (r0 + r) * 512 + c);
            __half2 h01 = *(__half2*)&tp[ch][i][0];
            __half2 h23 = *(__half2*)&tp[ch][i][1];
            float2 f01 = __half22float2(h01);
            float2 f23 = __half22float2(h23);
            float ri = rs[i];
            float4 o;
            o.x = fmaf(f01.x, ri * ci.x, xv.x);
            o.y = fmaf(f01.y, ri * ci.y, xv.y);
            o.z = fmaf(f23.x, ri * ci.z, xv.z);
            o.w = fmaf(f23.y, ri * ci.w, xv.w);
            *(float4*)(out + (r0 + r) * 512 + c) = o;
        }
    }
}

extern "C" void kernel_launch(void* const* d_in, const int* in_sizes, int n_in,
                              void* d_out, int out_size, void* d_ws, size_t ws_size,
                              hipStream_t stream) {
    const float* x     = (const float*)d_in[0];
    const float* xcons = (const float*)d_in[1];
    const float* cap   = (const float*)d_in[2];
    const float* W1    = (const float*)d_in[3];
    const float* b1    = (const float*)d_in[4];
    const float* W2    = (const float*)d_in[5];
    const float* b2    = (const float*)d_in[6];
    float* out         = (float*)d_out;
    float* ws          = (float*)d_ws;

    (void)in_sizes; (void)n_in; (void)out_size; (void)ws_size;

    prep_kernel<<<128, 256, 0, stream>>>(W1, W2, ws);

    hipFuncSetAttribute((const void*)fused_rgu,
                        hipFuncAttributeMaxDynamicSharedMemorySize, SMEM_BYTES);
    fused_rgu<<<NBLK, THREADS, SMEM_BYTES, stream>>>(
        x, xcons, cap, b1, b2, ws, out);
}